// Round 17
// baseline (75.101 us; speedup 1.0000x reference)
//
#include <hip/hip_runtime.h>

// DR splitting solver. BATCH=4096, N=96, M=48. prox_g1 affine: y = P x + Bmat p.
//   S=(I+Q)^{-1}; T=S Jx^T; K2=Jx T+diag(0,I32); R2=K2^{-1}[T^T|E];
//   P=diag(S,I)-[T;E^T]R2; Bmat=[-P[:,:64] | R2^T]
// Iterate 10x: y=Px+c; x += clamp(2y-x,l,u)-y; out=y[:64].
//
// Round-16 lesson: prep1's serial GJ chain (28 latency-exposed steps, 1 CU) is
// ~30us and un-fixable by occupancy tricks. Round-17: replace BOTH inversions
// with Newton-Schulz residual iteration (X<-X+X*E, E<-E^2; E0=I-cM elementwise;
// c from Gershgorin) -- all MFMA split-bf16 matmuls. E stays bitwise-symmetric
// so B-fragments read rows. T, K2 also MFMA. iter: x stored pre-split bf16
// hi/lo in LDS -> dot path is pure loads+MFMA (deletes ~300 VALU/lane/iter).

typedef __attribute__((ext_vector_type(8))) short short8v;
typedef __attribute__((ext_vector_type(4))) short short4v;
typedef __attribute__((ext_vector_type(4))) float float4v;

#define MFMA_BF16 __builtin_amdgcn_mfma_f32_16x16x32_bf16

__device__ __forceinline__ float dot4f(float4 a, float4 b) {
  return a.x*b.x + a.y*b.y + a.z*b.z + a.w*b.w;
}
__device__ __forceinline__ void ld4(const float* p, float* d) {
  float4 v = *(const float4*)p;
  d[0] = v.x; d[1] = v.y; d[2] = v.z; d[3] = v.w;
}
__device__ __forceinline__ void st4(float* p, const float* s) {
  *(float4*)p = make_float4(s[0], s[1], s[2], s[3]);
}
__device__ __forceinline__ unsigned short bf16h_rne(float v) {
  unsigned u = __float_as_uint(v);
  unsigned r = u + 0x7FFFu + ((u >> 16) & 1u);
  return (unsigned short)(r >> 16);
}
__device__ __forceinline__ float bf16_back(unsigned short h) {
  return __uint_as_float(((unsigned)h) << 16);
}
__device__ __forceinline__ void split1(float v, short* ph, short* pl) {
  unsigned short h = bf16h_rne(v);
  *ph = (short)h;
  *pl = (short)bf16h_rne(v - bf16_back(h));
}
__device__ __forceinline__ void split8(const float v[8], short8v &hi, short8v &lo) {
  #pragma unroll
  for (int j = 0; j < 8; ++j) {
    unsigned short h = bf16h_rne(v[j]);
    hi[j] = (short)h;
    lo[j] = (short)bf16h_rne(v[j] - bf16_back(h));
  }
}

// ---- one Newton-Schulz iteration: X <- X + X*E^T, E <- E*E^T (E symmetric).
// N_CT col-tiles, nwaves row-tiles. Arrays: f32 X stride 68; splits stride 72.
template<int N_CT>
__device__ __forceinline__ void ns_iter(
    float* __restrict__ sXf,
    short* __restrict__ sXh, short* __restrict__ sXl,
    short* __restrict__ sEh, short* __restrict__ sEl,
    int w, int lane, int nwaves)
{
  const int e = lane & 15, g = lane >> 4;
  const int row0 = 16 * w;
  const bool act = w < nwaves;
  float4v accX[N_CT], accE[N_CT];
  if (act) {
    short8v xah[2], xal[2], eah[2], eal[2];
    #pragma unroll
    for (int ks = 0; ks < 2; ++ks) {
      int off = (row0 + e)*72 + 32*ks + 8*g;
      xah[ks] = *(const short8v*)&sXh[off];
      xal[ks] = *(const short8v*)&sXl[off];
      eah[ks] = *(const short8v*)&sEh[off];
      eal[ks] = *(const short8v*)&sEl[off];
    }
    #pragma unroll
    for (int ct = 0; ct < N_CT; ++ct) {
      int col0 = 16 * ct;
      #pragma unroll
      for (int r = 0; r < 4; ++r)
        accX[ct][r] = sXf[(row0 + 4*g + r)*68 + col0 + e];
      accE[ct] = (float4v){0.f, 0.f, 0.f, 0.f};
      #pragma unroll
      for (int ks = 0; ks < 2; ++ks) {
        int boff = (col0 + e)*72 + 32*ks + 8*g;
        short8v ebh = *(const short8v*)&sEh[boff];
        short8v ebl = *(const short8v*)&sEl[boff];
        accX[ct] = MFMA_BF16(xah[ks], ebh, accX[ct], 0, 0, 0);
        accX[ct] = MFMA_BF16(xah[ks], ebl, accX[ct], 0, 0, 0);
        accX[ct] = MFMA_BF16(xal[ks], ebh, accX[ct], 0, 0, 0);
        accE[ct] = MFMA_BF16(eah[ks], ebh, accE[ct], 0, 0, 0);
        accE[ct] = MFMA_BF16(eah[ks], ebl, accE[ct], 0, 0, 0);
        accE[ct] = MFMA_BF16(eal[ks], ebh, accE[ct], 0, 0, 0);
      }
    }
  }
  __syncthreads();
  if (act) {
    #pragma unroll
    for (int ct = 0; ct < N_CT; ++ct) {
      int col0 = 16 * ct;
      #pragma unroll
      for (int r = 0; r < 4; ++r) {
        int row = row0 + 4*g + r, col = col0 + e;
        float xv = accX[ct][r];
        sXf[row*68 + col] = xv;
        split1(xv, &sXh[row*72 + col], &sXl[row*72 + col]);
        split1(accE[ct][r], &sEh[row*72 + col], &sEl[row*72 + col]);
      }
    }
  }
  __syncthreads();
}

// ---------------------------------------------------------------- prep1
// NS64 -> S; T = S Jx^T (MFMA); K2 = Jx T + E (MFMA); NS48 -> Ki. 256 thr.
__global__ __launch_bounds__(256, 1) void prep1_kernel(
    const float* __restrict__ Qg, const float* __restrict__ Ag,
    const float* __restrict__ Gg,
    float* __restrict__ Sg, float* __restrict__ Tg, float* __restrict__ Kig)
{
  __shared__ float sF1[64*68];       // M1 -> X(f32) -> (NS48) X48
  __shared__ float sF2[48*52];       // K2 f32
  __shared__ short sXh[64*72], sXl[64*72];   // X splits / S / T^T / X48
  __shared__ short sEh[64*72], sEl[64*72];   // E splits / Jx splits / E48
  __shared__ float sRed[72];

  const int tid  = threadIdx.x;
  const int w    = tid >> 6;
  const int lane = tid & 63;
  const int e    = lane & 15, g = lane >> 4;

  // ---- load M1 = Q + I
  {
    const float4* Q4 = (const float4*)Qg;
    #pragma unroll 1
    for (int t = tid; t < 1024; t += 256) {
      int i = t >> 4, kc = t & 15;
      float v[4]; ld4((const float*)&Q4[t], v);
      st4(&sF1[i*68 + kc*4], v);
    }
  }
  __syncthreads();
  if (tid < 64) sF1[tid*68 + tid] += 1.0f;
  __syncthreads();

  // ---- Gershgorin bound, c1 = 2/(1+B)
  if (tid < 64) {
    float s = 0.f;
    #pragma unroll 4
    for (int k = 0; k < 64; ++k) s += fabsf(sF1[tid*68 + k]);
    sRed[tid] = s;
  }
  __syncthreads();
  if (tid == 0) {
    float b = sRed[0];
    #pragma unroll 4
    for (int k = 1; k < 64; ++k) b = fmaxf(b, sRed[k]);
    sRed[64] = 2.0f / (1.0f + b);
  }
  __syncthreads();
  const float c1 = sRed[64];

  // ---- E0 = I - c1*M (split), X0 = c1*I (f32 + split)
  #pragma unroll 1
  for (int t = tid; t < 4096; t += 256) {
    int i = t >> 6, j = t & 63;
    float m = sF1[i*68 + j];
    float e0 = (i == j ? 1.0f : 0.0f) - c1 * m;
    split1(e0, &sEh[i*72 + j], &sEl[i*72 + j]);
    float x0 = (i == j) ? c1 : 0.0f;
    sF1[i*68 + j] = x0;
    split1(x0, &sXh[i*72 + j], &sXl[i*72 + j]);
  }
  __syncthreads();

  // ---- NS64: 8 iterations
  #pragma unroll 1
  for (int it = 0; it < 8; ++it)
    ns_iter<4>(sF1, sXh, sXl, sEh, sEl, w, lane, 4);

  // ---- write S to ws
  #pragma unroll 1
  for (int t = tid; t < 1024; t += 256) {
    int i = t >> 4, q = t & 15;
    float v[4]; ld4(&sF1[i*68 + q*4], v); st4(&Sg[i*64 + q*4], v);
  }

  // ---- stage Jx splits into sEh/sEl (rows 0..47, cols 0..63)
  #pragma unroll 1
  for (int t = tid; t < 3072; t += 256) {
    int a = t >> 6, k = t & 63;
    float v = (a < 16) ? Ag[a*64 + k] : Gg[(a - 16)*64 + k];
    split1(v, &sEh[a*72 + k], &sEl[a*72 + k]);
  }
  __syncthreads();

  // ---- T = S Jx^T (MFMA): A = S-split (sXh/sXl), B = Jx-split rows.
  {
    const int row0 = 16 * w;
    short8v sah[2], sal[2];
    #pragma unroll
    for (int ks = 0; ks < 2; ++ks) {
      int off = (row0 + e)*72 + 32*ks + 8*g;
      sah[ks] = *(const short8v*)&sXh[off];
      sal[ks] = *(const short8v*)&sXl[off];
    }
    float4v tacc[3];
    #pragma unroll
    for (int ct = 0; ct < 3; ++ct) {
      tacc[ct] = (float4v){0.f, 0.f, 0.f, 0.f};
      #pragma unroll
      for (int ks = 0; ks < 2; ++ks) {
        int boff = (16*ct + e)*72 + 32*ks + 8*g;
        short8v jbh = *(const short8v*)&sEh[boff];
        short8v jbl = *(const short8v*)&sEl[boff];
        tacc[ct] = MFMA_BF16(sah[ks], jbh, tacc[ct], 0, 0, 0);
        tacc[ct] = MFMA_BF16(sah[ks], jbl, tacc[ct], 0, 0, 0);
        tacc[ct] = MFMA_BF16(sal[ks], jbh, tacc[ct], 0, 0, 0);
      }
    }
    __syncthreads();   // S-split reads done before T^T overwrites sXh/sXl
    #pragma unroll
    for (int ct = 0; ct < 3; ++ct) {
      #pragma unroll
      for (int r = 0; r < 4; ++r) {
        int row = row0 + 4*g + r, col = 16*ct + e;
        float v = tacc[ct][r];
        Tg[row*48 + col] = v;
        split1(v, &sXh[col*72 + row], &sXl[col*72 + row]);  // T^T splits
      }
    }
  }
  __syncthreads();

  // ---- K2 = Jx T + diag(0,I32) (MFMA): A = Jx-split, B = T^T-split. w<3.
  if (w < 3) {
    const int row0 = 16 * w;
    short8v jah[2], jal[2];
    #pragma unroll
    for (int ks = 0; ks < 2; ++ks) {
      int off = (row0 + e)*72 + 32*ks + 8*g;
      jah[ks] = *(const short8v*)&sEh[off];
      jal[ks] = *(const short8v*)&sEl[off];
    }
    #pragma unroll
    for (int ct = 0; ct < 3; ++ct) {
      float4v kacc = (float4v){0.f, 0.f, 0.f, 0.f};
      #pragma unroll
      for (int ks = 0; ks < 2; ++ks) {
        int boff = (16*ct + e)*72 + 32*ks + 8*g;
        short8v tbh = *(const short8v*)&sXh[boff];
        short8v tbl = *(const short8v*)&sXl[boff];
        kacc = MFMA_BF16(jah[ks], tbh, kacc, 0, 0, 0);
        kacc = MFMA_BF16(jah[ks], tbl, kacc, 0, 0, 0);
        kacc = MFMA_BF16(jal[ks], tbh, kacc, 0, 0, 0);
      }
      #pragma unroll
      for (int r = 0; r < 4; ++r) {
        int a = row0 + 4*g + r, b = 16*ct + e;
        sF2[a*52 + b] = kacc[r] + ((a == b && a >= 16) ? 1.0f : 0.0f);
      }
    }
  }
  __syncthreads();

  // ---- symmetrize K2 (MFMA split noise breaks exact symmetry)
  {
    float sv[9];
    #pragma unroll
    for (int u = 0; u < 9; ++u) {
      int t = tid + 256*u;            // t < 2304
      int i = t / 48, j = t - 48*(t/48);
      sv[u] = 0.5f * (sF2[i*52 + j] + sF2[j*52 + i]);
    }
    __syncthreads();
    #pragma unroll
    for (int u = 0; u < 9; ++u) {
      int t = tid + 256*u;
      int i = t / 48, j = t - 48*(t/48);
      sF2[i*52 + j] = sv[u];
    }
  }
  __syncthreads();

  // ---- Gershgorin for K2, c2
  if (tid < 48) {
    float s = 0.f;
    #pragma unroll 4
    for (int k = 0; k < 48; ++k) s += fabsf(sF2[tid*52 + k]);
    sRed[tid] = s;
  }
  __syncthreads();
  if (tid == 0) {
    float b = sRed[0];
    #pragma unroll 4
    for (int k = 1; k < 48; ++k) b = fmaxf(b, sRed[k]);
    sRed[64] = 2.0f / (1.0f + b);
  }
  __syncthreads();
  const float c2 = sRed[64];

  // ---- E0/X0 for NS48 (+ zero pads cols 48..71)
  #pragma unroll 1
  for (int t = tid; t < 2304; t += 256) {
    int i = t / 48, j = t - 48*(t/48);
    float m = sF2[i*52 + j];
    float e0 = (i == j ? 1.0f : 0.0f) - c2 * m;
    split1(e0, &sEh[i*72 + j], &sEl[i*72 + j]);
    float x0 = (i == j) ? c2 : 0.0f;
    sF1[i*68 + j] = x0;
    split1(x0, &sXh[i*72 + j], &sXl[i*72 + j]);
  }
  #pragma unroll 1
  for (int t = tid; t < 48*24; t += 256) {
    int i = t / 24, j = 48 + (t - 24*(t/24));
    sXh[i*72 + j] = 0; sXl[i*72 + j] = 0;
    sEh[i*72 + j] = 0; sEl[i*72 + j] = 0;
  }
  __syncthreads();

  // ---- NS48: 15 iterations (margin for small lambda_min)
  #pragma unroll 1
  for (int it = 0; it < 15; ++it)
    ns_iter<3>(sF1, sXh, sXl, sEh, sEl, w, lane, 3);

  // ---- write Ki
  #pragma unroll 1
  for (int t = tid; t < 576; t += 256) {
    int k = t / 12, q = t - 12*(t/12);
    float v[4]; ld4(&sF1[k*68 + q*4], v); st4(&Kig[k*48 + q*4], v);
  }
}

// ---------------------------------------------------------------- prep2
// 4 blocks: each computes R2 (redundant, in LDS) + its 24-row slice of P/Bmat.
__global__ __launch_bounds__(256, 1) void prep2_kernel(
    const float* __restrict__ Sg, const float* __restrict__ Tg,
    const float* __restrict__ Kig,
    float* __restrict__ Pg, float* __restrict__ Bg)
{
  __shared__ float sT [64*48];
  __shared__ float sKi[48*48];
  __shared__ float sR2[48*96];
  __shared__ float sS [24*64];

  const int tid = threadIdx.x;
  const int b   = blockIdx.x;        // rows [24b, 24b+24)
  const int r0b = 24 * b;

  #pragma unroll 1
  for (int t = tid; t < 768; t += 256) {
    float v[4]; ld4(&Tg[t*4], v); st4(&sT[t*4], v);
  }
  #pragma unroll 1
  for (int t = tid; t < 576; t += 256) {
    float v[4]; ld4(&Kig[t*4], v); st4(&sKi[t*4], v);
  }
  #pragma unroll 1
  for (int t = tid; t < 384; t += 256) {
    int ri = t >> 4, q = t & 15;
    if (r0b + ri < 64) {
      float v[4]; ld4(&Sg[(r0b + ri)*64 + q*4], v); st4(&sS[ri*64 + q*4], v);
    }
  }
  __syncthreads();

  #pragma unroll 1
  for (int t = tid; t < 48*64; t += 256) {
    int k = t >> 6, c = t & 63;
    float acc = 0.0f;
    #pragma unroll 4
    for (int m = 0; m < 48; m += 4) {
      float kv[4], tv[4];
      ld4(&sKi[k*48 + m], kv); ld4(&sT[c*48 + m], tv);
      acc += kv[0]*tv[0] + kv[1]*tv[1] + kv[2]*tv[2] + kv[3]*tv[3];
    }
    sR2[k*96 + c] = acc;
  }
  #pragma unroll 1
  for (int t = tid; t < 48*32; t += 256) {
    int k = t >> 5, j = t & 31;
    sR2[k*96 + 64 + j] = sKi[k*48 + 16 + j];
  }
  __syncthreads();

  #pragma unroll 1
  for (int t = tid; t < 24*48; t += 256) {
    int c = r0b + t / 48, k = t - 48*(t/48);
    Bg[c*112 + 64 + k] = sR2[k*96 + c];
  }

  #pragma unroll 1
  for (int task = tid; task < 576; task += 256) {
    int ri = task / 24, jq = task - 24*(task/24);
    int i = r0b + ri, j0 = jq*4;
    if (i < 64) {
      float acc[4];
      #pragma unroll
      for (int q = 0; q < 4; ++q)
        acc[q] = (j0 < 64) ? sS[ri*64 + j0 + q] : 0.0f;
      #pragma unroll 4
      for (int m = 0; m < 48; m += 4) {
        float tv[4], rv[4][4];
        ld4(&sT[i*48 + m], tv);
        ld4(&sR2[(m+0)*96 + j0], rv[0]);
        ld4(&sR2[(m+1)*96 + j0], rv[1]);
        ld4(&sR2[(m+2)*96 + j0], rv[2]);
        ld4(&sR2[(m+3)*96 + j0], rv[3]);
        #pragma unroll
        for (int q = 0; q < 4; ++q)
          #pragma unroll
          for (int s = 0; s < 4; ++s)
            acc[q] -= tv[s] * rv[s][q];
      }
      #pragma unroll
      for (int q = 0; q < 4; ++q) {
        int j = j0 + q;
        Pg[i*96 + j] = acc[q];
        if (j < 64) Bg[i*112 + j] = -acc[q];
      }
    } else {
      int a = i - 64;
      #pragma unroll
      for (int q = 0; q < 4; ++q) {
        int j = j0 + q;
        float v = (i == j ? 1.0f : 0.0f) - sR2[(16 + a)*96 + j];
        Pg[i*96 + j] = v;
        if (j < 64) Bg[i*112 + j] = -v;
      }
    }
  }
}

// ---------------------------------------------------------------- kernel B
#define EB 16   // elements per block; grid = 256 blocks x 384 threads

__global__ __launch_bounds__(384, 1) void iter_kernel(
    const float* __restrict__ xg, const float* __restrict__ pg,
    const float* __restrict__ Pg, const float* __restrict__ Bg,
    float* __restrict__ outg)
{
  // x stored in LDS PRE-SPLIT as bf16 hi/lo (stride 104 shorts: 16B-aligned
  // b128 reads, 2-way bank max). Dot path = pure short8 loads + MFMA.
  __shared__ short sXh[2][EB*104], sXl[2][EB*104];
  __shared__ float sPar[EB][128];

  const int tid   = threadIdx.x;    // 0..383
  const int gbase = blockIdx.x * EB;
  const int w     = tid >> 6;
  const int lane  = tid & 63;
  const int e     = lane & 15;
  const int g     = lane >> 4;
  const int row0  = 16 * w;

  // stage x: 1 float4/thread -> split -> short4 hi/lo
  {
    int ee = tid / 24, kc = tid - 24 * (tid / 24);
    float4 v = ((const float4*)xg)[gbase*24 + tid];
    float vv[4] = {v.x, v.y, v.z, v.w};
    short4v hv, lv;
    #pragma unroll
    for (int j = 0; j < 4; ++j) {
      unsigned short h = bf16h_rne(vv[j]);
      hv[j] = (short)h;
      lv[j] = (short)bf16h_rne(vv[j] - bf16_back(h));
    }
    *(short4v*)&sXh[0][ee*104 + kc*4] = hv;
    *(short4v*)&sXl[0][ee*104 + kc*4] = lv;
  }
  for (int t = tid; t < EB*28; t += 384) {
    int ee = t / 28, jc = t - 28 * (t / 28);
    *(float4*)&sPar[ee][jc*4] = ((const float4*)pg)[gbase*28 + t];
  }
  if (tid < EB*4) {
    int ee = tid >> 2, jc = tid & 3;
    *(float4*)&sPar[ee][112 + jc*4] = make_float4(0.f, 0.f, 0.f, 0.f);
  }

  // P fragments (A operand), hi/lo, register-resident (24 VGPRs)
  short8v pfh[3], pfl[3];
  #pragma unroll
  for (int kc = 0; kc < 3; ++kc) {
    float v[8];
    const float* src = Pg + (row0 + e)*96 + 32*kc + 8*g;
    ld4(src, v); ld4(src + 4, v + 4);
    split8(v, pfh[kc], pfl[kc]);
  }

  __syncthreads();

  // c = Bmat @ parms via MFMA (K=112 zero-padded to 128)
  float4v cfrag = {0.f, 0.f, 0.f, 0.f};
  #pragma unroll
  for (int kc = 0; kc < 4; ++kc) {
    const int kbase = 32*kc + 8*g;
    float v[8];
    short8v ah, al, bh, bl;
    if (kbase < 112) {
      const float* src = Bg + (row0 + e)*112 + kbase;
      ld4(src, v); ld4(src + 4, v + 4);
    } else {
      #pragma unroll
      for (int j = 0; j < 8; ++j) v[j] = 0.f;
    }
    split8(v, ah, al);
    ld4(&sPar[e][kbase], v); ld4(&sPar[e][kbase + 4], v + 4);
    split8(v, bh, bl);
    cfrag = MFMA_BF16(ah, bh, cfrag, 0, 0, 0);
    cfrag = MFMA_BF16(ah, bl, cfrag, 0, 0, 0);
    cfrag = MFMA_BF16(al, bh, cfrag, 0, 0, 0);
  }

  const float lob = (row0 < 64) ? -1000.f : 0.f;
  int cur = 0;

  #pragma unroll 1
  for (int it = 0; it < 10; ++it) {
    const short* xhp = &sXh[cur][0];
    const short* xlp = &sXl[cur][0];
    // 3 independent accumulation chains
    float4v accs[3];
    accs[0] = cfrag;
    accs[1] = (float4v){0.f, 0.f, 0.f, 0.f};
    accs[2] = (float4v){0.f, 0.f, 0.f, 0.f};
    #pragma unroll
    for (int kc = 0; kc < 3; ++kc) {
      int off = e*104 + 32*kc + 8*g;
      short8v xh = *(const short8v*)&xhp[off];
      short8v xl = *(const short8v*)&xlp[off];
      accs[kc] = MFMA_BF16(pfh[kc], xh, accs[kc], 0, 0, 0);
      accs[kc] = MFMA_BF16(pfh[kc], xl, accs[kc], 0, 0, 0);
      accs[kc] = MFMA_BF16(pfl[kc], xh, accs[kc], 0, 0, 0);
    }
    float4v acc = accs[0] + accs[1] + accs[2];

    if (it < 9) {
      short4v hv, lv;
      #pragma unroll
      for (int r = 0; r < 4; ++r) {
        int row = row0 + 4*g + r;
        float y  = acc[r];
        float xo = bf16_back((unsigned short)xhp[e*104 + row]) +
                   bf16_back((unsigned short)xlp[e*104 + row]);
        float z  = fminf(fmaxf(2.f*y - xo, lob), 1000.f);
        float xn = xo + z - y;
        unsigned short h = bf16h_rne(xn);
        hv[r] = (short)h;
        lv[r] = (short)bf16h_rne(xn - bf16_back(h));
      }
      *(short4v*)&sXh[cur ^ 1][e*104 + row0 + 4*g] = hv;
      *(short4v*)&sXl[cur ^ 1][e*104 + row0 + 4*g] = lv;
      __syncthreads();
      cur ^= 1;
    } else {
      if (row0 < 64) {
        *(float4*)&outg[(gbase + e)*64 + row0 + 4*g] =
            make_float4(acc[0], acc[1], acc[2], acc[3]);
      }
    }
  }
}

// ---------------------------------------------------------------- launch
extern "C" void kernel_launch(void* const* d_in, const int* in_sizes, int n_in,
                              void* d_out, int out_size, void* d_ws, size_t ws_size,
                              hipStream_t stream) {
  const float* x     = (const float*)d_in[0];   // (4096, 96)
  const float* parms = (const float*)d_in[1];   // (4096, 112)
  const float* Qg    = (const float*)d_in[2];   // (64, 64)
  const float* Ag    = (const float*)d_in[3];   // (16, 64)
  const float* Gg    = (const float*)d_in[4];   // (32, 64)
  float* out = (float*)d_out;                   // (4096, 64)

  float* ws  = (float*)d_ws;
  float* Pg  = ws;                  // 96*96  = 9216
  float* Bg  = ws + 9216;           // 96*112 = 10752
  float* Sg  = ws + 19968;          // 64*64  = 4096
  float* Tg  = ws + 24064;          // 64*48  = 3072
  float* Kig = ws + 27136;          // 48*48  = 2304

  prep1_kernel<<<1, 256, 0, stream>>>(Qg, Ag, Gg, Sg, Tg, Kig);
  prep2_kernel<<<4, 256, 0, stream>>>(Sg, Tg, Kig, Pg, Bg);
  iter_kernel<<<4096 / EB, 384, 0, stream>>>(x, parms, Pg, Bg, out);
}

// Round 18
// 54.412 us; speedup vs baseline: 1.3802x; 1.3802x over previous
//
#include <hip/hip_runtime.h>

// DR splitting solver. BATCH=4096, N=96, M=48. prox_g1 affine: y = P x + Bmat p.
//   S=(I+Q)^{-1}; T=S Jx^T; K2=Jx T+diag(0,I32); R2=K2^{-1}[T^T|E];
//   P=diag(S,I)-[T;E^T]R2; Bmat=[-P[:,:64] | R2^T]
// Iterate 10x: y=Px+c; x += clamp(2y-x,l,u)-y; out=y[:64].
//
// Round-17 lesson: NS-MFMA prep regressed (80 scalar LDS stores/thread/iter in
// the split writeback; 23 iters x 2 barriers no shorter than GJ) -> prep1/prep2
// reverted to round-16 GJ (37 + 2.5us proven). Round-18 iter: xo kept in 4 f32
// REGISTERS across iterations (same lane computes and updates each (row,e) --
// D-layout == update layout), parms/B read globally (sPar staging deleted).
// Per-iter LDS: 2 short4 stores + 6 b128 reads + 1 barrier.

typedef __attribute__((ext_vector_type(8))) short short8v;
typedef __attribute__((ext_vector_type(4))) short short4v;
typedef __attribute__((ext_vector_type(4))) float float4v;

#define MFMA_BF16 __builtin_amdgcn_mfma_f32_16x16x32_bf16

__device__ __forceinline__ void ld4(const float* p, float* d) {
  float4 v = *(const float4*)p;
  d[0] = v.x; d[1] = v.y; d[2] = v.z; d[3] = v.w;
}
__device__ __forceinline__ void st4(float* p, const float* s) {
  *(float4*)p = make_float4(s[0], s[1], s[2], s[3]);
}
__device__ __forceinline__ float fastrcp(float x) {
  float r = __builtin_amdgcn_rcpf(x);
  return r * (2.0f - x * r);
}
__device__ __forceinline__ void mm4(float W[4][4], const float A[4][4], const float B[4][4]) {
  #pragma unroll
  for (int r = 0; r < 4; ++r)
    #pragma unroll
    for (int q = 0; q < 4; ++q) {
      float s = A[r][0]*B[0][q];
      #pragma unroll
      for (int k = 1; k < 4; ++k) s += A[r][k]*B[k][q];
      W[r][q] = s;
    }
}
__device__ __forceinline__ void inv4(float D[4][4]) {
  #pragma unroll
  for (int p = 0; p < 4; ++p) {
    float pi = fastrcp(D[p][p]);
    D[p][p] = pi;
    #pragma unroll
    for (int q = 0; q < 4; ++q) if (q != p) D[p][q] *= pi;
    #pragma unroll
    for (int i = 0; i < 4; ++i) if (i != p) {
      float f = D[i][p];
      #pragma unroll
      for (int q = 0; q < 4; ++q) if (q != p) D[i][q] -= f * D[p][q];
      D[i][p] = -f * pi;
    }
  }
}
__device__ __forceinline__ unsigned short bf16h_rne(float v) {
  unsigned u = __float_as_uint(v);
  unsigned r = u + 0x7FFFu + ((u >> 16) & 1u);
  return (unsigned short)(r >> 16);
}
__device__ __forceinline__ float bf16_back(unsigned short h) {
  return __uint_as_float(((unsigned)h) << 16);
}
__device__ __forceinline__ void split8(const float v[8], short8v &hi, short8v &lo) {
  #pragma unroll
  for (int j = 0; j < 8; ++j) {
    unsigned short h = bf16h_rne(v[j]);
    hi[j] = (short)h;
    lo[j] = (short)bf16h_rne(v[j] - bf16_back(h));
  }
}

// double-buffered block-GJ step, stride 68 (64x64), 256 threads
__device__ __forceinline__ void gj_step64(const float* __restrict__ src,
                                          float* __restrict__ dst,
                                          int b, int ig, int jg) {
  float D[4][4], C[4][4], R[4][4], T4[4][4], W[4][4];
  #pragma unroll
  for (int r = 0; r < 4; ++r) {
    ld4(&src[(4*b + r)*68 + 4*b],  D[r]);
    ld4(&src[(4*ig + r)*68 + 4*b], C[r]);
    ld4(&src[(4*b + r)*68 + 4*jg], R[r]);
    ld4(&src[(4*ig + r)*68 + 4*jg], T4[r]);
  }
  inv4(D);
  if (ig == b) {
    if (jg == b) {
      #pragma unroll
      for (int r = 0; r < 4; ++r)
        #pragma unroll
        for (int q = 0; q < 4; ++q) W[r][q] = D[r][q];
    } else {
      mm4(W, D, R);
    }
  } else {
    float E[4][4];
    mm4(E, C, D);
    if (jg == b) {
      #pragma unroll
      for (int r = 0; r < 4; ++r)
        #pragma unroll
        for (int q = 0; q < 4; ++q) W[r][q] = -E[r][q];
    } else {
      #pragma unroll
      for (int r = 0; r < 4; ++r)
        #pragma unroll
        for (int q = 0; q < 4; ++q) {
          float s = T4[r][q];
          #pragma unroll
          for (int k = 0; k < 4; ++k) s -= E[r][k] * R[k][q];
          W[r][q] = s;
        }
    }
  }
  #pragma unroll
  for (int r = 0; r < 4; ++r) st4(&dst[(4*ig + r)*68 + 4*jg], W[r]);
  __syncthreads();
}

// double-buffered block-GJ step, stride 52 (48x48), threads 0..143
__device__ __forceinline__ void gj_step48(const float* __restrict__ src,
                                          float* __restrict__ dst,
                                          int b, int tid) {
  const bool act = tid < 144;
  const int ig = tid / 12, jg = tid - (tid / 12) * 12;
  float D[4][4], C[4][4], R[4][4], T4[4][4], W[4][4];
  if (act) {
    #pragma unroll
    for (int r = 0; r < 4; ++r) {
      ld4(&src[(4*b + r)*52 + 4*b],  D[r]);
      ld4(&src[(4*ig + r)*52 + 4*b], C[r]);
      ld4(&src[(4*b + r)*52 + 4*jg], R[r]);
      ld4(&src[(4*ig + r)*52 + 4*jg], T4[r]);
    }
    inv4(D);
    if (ig == b) {
      if (jg == b) {
        #pragma unroll
        for (int r = 0; r < 4; ++r)
          #pragma unroll
          for (int q = 0; q < 4; ++q) W[r][q] = D[r][q];
      } else {
        mm4(W, D, R);
      }
    } else {
      float E[4][4];
      mm4(E, C, D);
      if (jg == b) {
        #pragma unroll
        for (int r = 0; r < 4; ++r)
          #pragma unroll
          for (int q = 0; q < 4; ++q) W[r][q] = -E[r][q];
      } else {
        #pragma unroll
        for (int r = 0; r < 4; ++r)
          #pragma unroll
          for (int q = 0; q < 4; ++q) {
            float s = T4[r][q];
            #pragma unroll
            for (int k = 0; k < 4; ++k) s -= E[r][k] * R[k][q];
            W[r][q] = s;
          }
      }
    }
    #pragma unroll
    for (int r = 0; r < 4; ++r) st4(&dst[(4*ig + r)*52 + 4*jg], W[r]);
  }
  __syncthreads();
}

// ---------------------------------------------------------------- prep1
// Serial part: GJ64 -> T -> K2 -> GJ48. Writes S, T, Ki to workspace.
__global__ __launch_bounds__(256, 1) void prep1_kernel(
    const float* __restrict__ Qg, const float* __restrict__ Ag,
    const float* __restrict__ Gg,
    float* __restrict__ Sg, float* __restrict__ Tg, float* __restrict__ Kig)
{
  __shared__ float sMa[64*68];   // M1 ping -> S
  __shared__ float sMb[64*68];   // M1 pong -> T (stride 48)
  __shared__ float sK [48*52];   // K2 ping -> Ki
  __shared__ float sJx[48*68];   // Jx staged; also GJ48 pong (48*52)

#define SM_(i,j) sMa[(i)*68+(j)]
#define TT_(i,j) sMb[(i)*48+(j)]
#define SK_(i,j) sK[(i)*52+(j)]
#define JX_(a,k) sJx[(a)*68+(k)]

  const int tid = threadIdx.x;
  const int ig = tid >> 4, jg = tid & 15;

  // stage Jx = [A;G] and M1 = Q + I
  {
    const float4* A4 = (const float4*)Ag;
    const float4* G4 = (const float4*)Gg;
    {
      int a = tid >> 4, kc = tid & 15;
      float v[4]; ld4((const float*)&A4[tid], v);
      st4(&JX_(a, kc*4), v);
    }
    for (int t = tid; t < 512; t += 256) {
      int a = t >> 4, kc = t & 15;
      float v[4]; ld4((const float*)&G4[t], v);
      st4(&JX_(16 + a, kc*4), v);
    }
    const float4* Q4 = (const float4*)Qg;
    for (int t = tid; t < 1024; t += 256) {
      int i = t >> 4, kc = t & 15;
      float v[4]; ld4((const float*)&Q4[t], v);
      st4(&SM_(i, kc*4), v);
    }
  }
  __syncthreads();
  if (tid < 64) SM_(tid, tid) += 1.0f;
  __syncthreads();

  // block-GJ 64 (dbuf, 16 steps) -> S in sMa
  #pragma unroll 1
  for (int p = 0; p < 8; ++p) {
    gj_step64(sMa, sMb, 2*p,     ig, jg);
    gj_step64(sMb, sMa, 2*p + 1, ig, jg);
  }

  // T = S Jx^T : 4x3 register tile/thread
  {
    const int i0 = 4*ig, j0 = 3*jg;
    float acc[4][3] = {};
    #pragma unroll 4
    for (int kq = 0; kq < 16; ++kq) {
      float sv[4][4], jv[3][4];
      ld4(&SM_(i0+0, kq*4), sv[0]); ld4(&SM_(i0+1, kq*4), sv[1]);
      ld4(&SM_(i0+2, kq*4), sv[2]); ld4(&SM_(i0+3, kq*4), sv[3]);
      ld4(&JX_(j0+0, kq*4), jv[0]); ld4(&JX_(j0+1, kq*4), jv[1]);
      ld4(&JX_(j0+2, kq*4), jv[2]);
      #pragma unroll
      for (int r = 0; r < 4; ++r)
        #pragma unroll
        for (int c = 0; c < 3; ++c)
          #pragma unroll
          for (int s = 0; s < 4; ++s)
            acc[r][c] += sv[r][s] * jv[c][s];
    }
    __syncthreads();
    #pragma unroll
    for (int r = 0; r < 4; ++r)
      #pragma unroll
      for (int c = 0; c < 3; ++c)
        TT_(i0+r, j0+c) = acc[r][c];
  }
  __syncthreads();

  // K2 = Jx T + diag(0,I32)  (192 threads, 3x4 tiles)
  if (tid < 192) {
    int ag = tid / 12, bg = tid - ag*12;
    int a0 = ag*3, b0 = bg*4;
    float acc[3][4] = {};
    #pragma unroll 4
    for (int k = 0; k < 64; ++k) {
      float4 tb = *(const float4*)&TT_(k,b0);
      #pragma unroll
      for (int r = 0; r < 3; ++r) {
        float jv = JX_(a0 + r, k);
        acc[r][0] += jv*tb.x; acc[r][1] += jv*tb.y;
        acc[r][2] += jv*tb.z; acc[r][3] += jv*tb.w;
      }
    }
    #pragma unroll
    for (int r = 0; r < 3; ++r)
      #pragma unroll
      for (int q = 0; q < 4; ++q) {
        int a = a0 + r, b = b0 + q;
        SK_(a,b) = acc[r][q] + ((a == b && a >= 16) ? 1.0f : 0.0f);
      }
  }
  __syncthreads();

  // block-GJ 48 (dbuf; pong overlays dead Jx region) -> Ki in sK
  {
    float* KP = sJx;   // 48*52 = 2496 <= 48*68
    #pragma unroll 1
    for (int p = 0; p < 6; ++p) {
      gj_step48(sK, KP, 2*p,     tid);
      gj_step48(KP, sK, 2*p + 1, tid);
    }
  }

  // write S (64x64), T (64x48), Ki (48x48) to ws
  #pragma unroll 1
  for (int t = tid; t < 1024; t += 256) {
    int i = t >> 4, q = t & 15;
    float v[4]; ld4(&SM_(i, q*4), v); st4(&Sg[i*64 + q*4], v);
  }
  #pragma unroll 1
  for (int t = tid; t < 768; t += 256) {
    int i = t / 12, q = t - 12*(t/12);
    float v[4]; ld4(&TT_(i, q*4), v); st4(&Tg[i*48 + q*4], v);
  }
  #pragma unroll 1
  for (int t = tid; t < 576; t += 256) {
    int k = t / 12, q = t - 12*(t/12);
    float v[4]; ld4(&SK_(k, q*4), v); st4(&Kig[k*48 + q*4], v);
  }
#undef SM_
#undef TT_
#undef SK_
#undef JX_
}

// ---------------------------------------------------------------- prep2
// 4 blocks: each computes R2 (redundant, in LDS) + its 24-row slice of P/Bmat.
__global__ __launch_bounds__(256, 1) void prep2_kernel(
    const float* __restrict__ Sg, const float* __restrict__ Tg,
    const float* __restrict__ Kig,
    float* __restrict__ Pg, float* __restrict__ Bg)
{
  __shared__ float sT [64*48];
  __shared__ float sKi[48*48];
  __shared__ float sR2[48*96];
  __shared__ float sS [24*64];

  const int tid = threadIdx.x;
  const int b   = blockIdx.x;        // rows [24b, 24b+24)
  const int r0b = 24 * b;

  #pragma unroll 1
  for (int t = tid; t < 768; t += 256) {
    float v[4]; ld4(&Tg[t*4], v); st4(&sT[t*4], v);
  }
  #pragma unroll 1
  for (int t = tid; t < 576; t += 256) {
    float v[4]; ld4(&Kig[t*4], v); st4(&sKi[t*4], v);
  }
  #pragma unroll 1
  for (int t = tid; t < 384; t += 256) {
    int ri = t >> 4, q = t & 15;
    if (r0b + ri < 64) {
      float v[4]; ld4(&Sg[(r0b + ri)*64 + q*4], v); st4(&sS[ri*64 + q*4], v);
    }
  }
  __syncthreads();

  #pragma unroll 1
  for (int t = tid; t < 48*64; t += 256) {
    int k = t >> 6, c = t & 63;
    float acc = 0.0f;
    #pragma unroll 4
    for (int m = 0; m < 48; m += 4) {
      float kv[4], tv[4];
      ld4(&sKi[k*48 + m], kv); ld4(&sT[c*48 + m], tv);
      acc += kv[0]*tv[0] + kv[1]*tv[1] + kv[2]*tv[2] + kv[3]*tv[3];
    }
    sR2[k*96 + c] = acc;
  }
  #pragma unroll 1
  for (int t = tid; t < 48*32; t += 256) {
    int k = t >> 5, j = t & 31;
    sR2[k*96 + 64 + j] = sKi[k*48 + 16 + j];
  }
  __syncthreads();

  #pragma unroll 1
  for (int t = tid; t < 24*48; t += 256) {
    int c = r0b + t / 48, k = t - 48*(t/48);
    Bg[c*112 + 64 + k] = sR2[k*96 + c];
  }

  #pragma unroll 1
  for (int task = tid; task < 576; task += 256) {
    int ri = task / 24, jq = task - 24*(task/24);
    int i = r0b + ri, j0 = jq*4;
    if (i < 64) {
      float acc[4];
      #pragma unroll
      for (int q = 0; q < 4; ++q)
        acc[q] = (j0 < 64) ? sS[ri*64 + j0 + q] : 0.0f;
      #pragma unroll 4
      for (int m = 0; m < 48; m += 4) {
        float tv[4], rv[4][4];
        ld4(&sT[i*48 + m], tv);
        ld4(&sR2[(m+0)*96 + j0], rv[0]);
        ld4(&sR2[(m+1)*96 + j0], rv[1]);
        ld4(&sR2[(m+2)*96 + j0], rv[2]);
        ld4(&sR2[(m+3)*96 + j0], rv[3]);
        #pragma unroll
        for (int q = 0; q < 4; ++q)
          #pragma unroll
          for (int s = 0; s < 4; ++s)
            acc[q] -= tv[s] * rv[s][q];
      }
      #pragma unroll
      for (int q = 0; q < 4; ++q) {
        int j = j0 + q;
        Pg[i*96 + j] = acc[q];
        if (j < 64) Bg[i*112 + j] = -acc[q];
      }
    } else {
      int a = i - 64;
      #pragma unroll
      for (int q = 0; q < 4; ++q) {
        int j = j0 + q;
        float v = (i == j ? 1.0f : 0.0f) - sR2[(16 + a)*96 + j];
        Pg[i*96 + j] = v;
        if (j < 64) Bg[i*112 + j] = -v;
      }
    }
  }
}

// ---------------------------------------------------------------- kernel B
#define EB 16   // elements per block; grid = 256 blocks x 384 threads

__global__ __launch_bounds__(384, 1) void iter_kernel(
    const float* __restrict__ xg, const float* __restrict__ pg,
    const float* __restrict__ Pg, const float* __restrict__ Bg,
    float* __restrict__ outg)
{
  // MFMA split-bf16. Wave w owns row-tile 16w. xo for each (row,e) lives in
  // the SAME lane that computes acc for it (D-layout == update layout) -> kept
  // in 4 f32 registers across all 10 iterations; LDS holds only the bf16
  // hi/lo splits of x for the B-operand reads (double-buffered).
  __shared__ short sXh[2][EB*104], sXl[2][EB*104];

  const int tid   = threadIdx.x;    // 0..383
  const int gbase = blockIdx.x * EB;
  const int w     = tid >> 6;
  const int lane  = tid & 63;
  const int e     = lane & 15;
  const int g     = lane >> 4;
  const int row0  = 16 * w;
  const int rbase = row0 + 4*g;     // my 4 rows (for D/output/x-state)

  // P fragments (A operand), hi/lo, register-resident (24 VGPRs)
  short8v pfh[3], pfl[3];
  #pragma unroll
  for (int kc = 0; kc < 3; ++kc) {
    float v[8];
    const float* src = Pg + (row0 + e)*96 + 32*kc + 8*g;
    ld4(src, v); ld4(src + 4, v + 4);
    split8(v, pfh[kc], pfl[kc]);
  }

  // x state: my 4 values in registers; splits to LDS buffer 0
  float xo[4];
  ld4(xg + (size_t)(gbase + e)*96 + rbase, xo);
  {
    short4v hv, lv;
    #pragma unroll
    for (int r = 0; r < 4; ++r) {
      unsigned short h = bf16h_rne(xo[r]);
      hv[r] = (short)h;
      lv[r] = (short)bf16h_rne(xo[r] - bf16_back(h));
    }
    *(short4v*)&sXh[0][e*104 + rbase] = hv;
    *(short4v*)&sXl[0][e*104 + rbase] = lv;
  }

  // c = Bmat @ parms via MFMA (global reads; K=112 padded to 128)
  float4v cfrag = {0.f, 0.f, 0.f, 0.f};
  #pragma unroll
  for (int kc = 0; kc < 4; ++kc) {
    const int kbase = 32*kc + 8*g;
    float v[8];
    short8v ah, al, bh, bl;
    if (kbase < 112) {
      const float* src = Bg + (row0 + e)*112 + kbase;
      ld4(src, v); ld4(src + 4, v + 4);
    } else {
      #pragma unroll
      for (int j = 0; j < 8; ++j) v[j] = 0.f;
    }
    split8(v, ah, al);
    if (kbase < 112) {
      const float* src = pg + (size_t)(gbase + e)*112 + kbase;
      ld4(src, v); ld4(src + 4, v + 4);
    } else {
      #pragma unroll
      for (int j = 0; j < 8; ++j) v[j] = 0.f;
    }
    split8(v, bh, bl);
    cfrag = MFMA_BF16(ah, bh, cfrag, 0, 0, 0);
    cfrag = MFMA_BF16(ah, bl, cfrag, 0, 0, 0);
    cfrag = MFMA_BF16(al, bh, cfrag, 0, 0, 0);
  }

  __syncthreads();   // x splits visible

  const float lob = (row0 < 64) ? -1000.f : 0.f;
  int cur = 0;

  #pragma unroll 1
  for (int it = 0; it < 10; ++it) {
    const short* xhp = &sXh[cur][0];
    const short* xlp = &sXl[cur][0];
    float4v accs0 = cfrag;
    float4v accs1 = {0.f, 0.f, 0.f, 0.f};
    float4v accs2 = {0.f, 0.f, 0.f, 0.f};
    {
      int off = e*104 + 8*g;
      short8v xh0 = *(const short8v*)&xhp[off];
      short8v xl0 = *(const short8v*)&xlp[off];
      short8v xh1 = *(const short8v*)&xhp[off + 32];
      short8v xl1 = *(const short8v*)&xlp[off + 32];
      short8v xh2 = *(const short8v*)&xhp[off + 64];
      short8v xl2 = *(const short8v*)&xlp[off + 64];
      accs0 = MFMA_BF16(pfh[0], xh0, accs0, 0, 0, 0);
      accs1 = MFMA_BF16(pfh[1], xh1, accs1, 0, 0, 0);
      accs2 = MFMA_BF16(pfh[2], xh2, accs2, 0, 0, 0);
      accs0 = MFMA_BF16(pfh[0], xl0, accs0, 0, 0, 0);
      accs1 = MFMA_BF16(pfh[1], xl1, accs1, 0, 0, 0);
      accs2 = MFMA_BF16(pfh[2], xl2, accs2, 0, 0, 0);
      accs0 = MFMA_BF16(pfl[0], xh0, accs0, 0, 0, 0);
      accs1 = MFMA_BF16(pfl[1], xh1, accs1, 0, 0, 0);
      accs2 = MFMA_BF16(pfl[2], xh2, accs2, 0, 0, 0);
    }
    float4v acc = accs0 + accs1 + accs2;

    if (it < 9) {
      short4v hv, lv;
      #pragma unroll
      for (int r = 0; r < 4; ++r) {
        float y = acc[r];
        float z = fminf(fmaxf(2.f*y - xo[r], lob), 1000.f);
        float xn = xo[r] + z - y;
        xo[r] = xn;
        unsigned short h = bf16h_rne(xn);
        hv[r] = (short)h;
        lv[r] = (short)bf16h_rne(xn - bf16_back(h));
      }
      *(short4v*)&sXh[cur ^ 1][e*104 + rbase] = hv;
      *(short4v*)&sXl[cur ^ 1][e*104 + rbase] = lv;
      __syncthreads();
      cur ^= 1;
    } else {
      if (row0 < 64) {
        *(float4*)&outg[(gbase + e)*64 + rbase] =
            make_float4(acc[0], acc[1], acc[2], acc[3]);
      }
    }
  }
}

// ---------------------------------------------------------------- launch
extern "C" void kernel_launch(void* const* d_in, const int* in_sizes, int n_in,
                              void* d_out, int out_size, void* d_ws, size_t ws_size,
                              hipStream_t stream) {
  const float* x     = (const float*)d_in[0];   // (4096, 96)
  const float* parms = (const float*)d_in[1];   // (4096, 112)
  const float* Qg    = (const float*)d_in[2];   // (64, 64)
  const float* Ag    = (const float*)d_in[3];   // (16, 64)
  const float* Gg    = (const float*)d_in[4];   // (32, 64)
  float* out = (float*)d_out;                   // (4096, 64)

  float* ws  = (float*)d_ws;
  float* Pg  = ws;                  // 96*96  = 9216
  float* Bg  = ws + 9216;           // 96*112 = 10752
  float* Sg  = ws + 19968;          // 64*64  = 4096
  float* Tg  = ws + 24064;          // 64*48  = 3072
  float* Kig = ws + 27136;          // 48*48  = 2304

  prep1_kernel<<<1, 256, 0, stream>>>(Qg, Ag, Gg, Sg, Tg, Kig);
  prep2_kernel<<<4, 256, 0, stream>>>(Sg, Tg, Kig, Pg, Bg);
  iter_kernel<<<4096 / EB, 384, 0, stream>>>(x, parms, Pg, Bg, out);
}